// Round 6
// baseline (836.053 us; speedup 1.0000x reference)
//
#include <hip/hip_runtime.h>

#define EPS 1e-5f
#define WROWS 384   // LDS window rows; (384+1)*64B = 24.6KB -> 6 blocks/CU [R17: was 448/5]

typedef __attribute__((ext_vector_type(8))) short short8;            // 8 bf16 MFMA frag
typedef __attribute__((ext_vector_type(4))) float floatx4;           // MFMA C/D frag
typedef __attribute__((ext_vector_type(8))) unsigned short ushort8;
typedef __attribute__((ext_vector_type(4))) unsigned short ushortv4;

// packed-weight element offsets (compile-time)
#define O_S1  0
#define O_S2  4096
#define O_DN  (O_S2 + 27648)
#define O_R1A (O_DN + 8192)
#define O_R1B (O_R1A + 27648)
#define O_R2A (O_R1B + 27648)
#define O_R2B (O_R2A + 27648)
#define WP_TOTAL (O_R2B + 27648)

// async global->LDS 16B (linear LDS dest = wave-uniform base + lane*16)
#define GLL16(g, l)                                                       \
    __builtin_amdgcn_global_load_lds(                                     \
        (const __attribute__((address_space(1))) void*)(g),               \
        (__attribute__((address_space(3))) void*)(l), 16, 0, 0)

// bf16 <-> f32 (RTNE)
__device__ __forceinline__ unsigned short f2bf(float f) {
    union { float f; unsigned u; } x; x.f = f;
    unsigned r = x.u + 0x7fffu + ((x.u >> 16) & 1u);
    return (unsigned short)(r >> 16);
}
__device__ __forceinline__ float bf2f(unsigned short b) {
    union { unsigned u; float f; } x; x.u = ((unsigned)b) << 16;
    return x.f;
}

// XCD-aware block remap [R8: halved FETCH]
__device__ __forceinline__ int xcd_swizzle(int nb) {
    int b = (int)blockIdx.x;
    int q = nb >> 3, r = nb & 7;
    int x = b & 7, i = b >> 3;
    return x * q + (x < r ? x : r) + i;
}

// guarded 16B A-fragment gather from GLOBAL (fallback path, rare)
__device__ __forceinline__ short8 gath(const unsigned short* __restrict__ x,
                                       int ii, int q) {
    short8 z = {};
    return (ii >= 0) ? *(const short8*)(x + (size_t)ii * 32 + q * 8) : z;
}

// ---------------------------------------------------------------------------
// Per-(block,group) window bounds: one wave per window, reduced via shfl.
// All convs at 128-row blocks. nbr1's result reused by 4 convs. [R12]
template <int ZG, int TPG>
__device__ __forceinline__ void wmm_calc(
    const int* __restrict__ nbr, int N, int t, int* __restrict__ out)
{
    int ln = t & 63, wv = t >> 6;
    int lb = wv / ZG, c = wv - lb * ZG;
    int base = lb * 128;
    int mn = 0x7fffffff, mx = -1;
#pragma unroll
    for (int j = 0; j < TPG; ++j) {
#pragma unroll
        for (int h = 0; h < 2; ++h) {
            int r = base + h * 64 + ln;
            if (r < N) {
                int v = nbr[(size_t)(c + ZG * j) * N + r];
                if (v >= 0) { mn = min(mn, v); mx = max(mx, v); }
            }
        }
    }
#pragma unroll
    for (int off = 32; off >= 1; off >>= 1) {
        mn = min(mn, __shfl_down(mn, off));
        mx = max(mx, __shfl_down(mx, off));
    }
    if (ln == 0) { out[wv * 2] = (mx < 0) ? 0 : mn; out[wv * 2 + 1] = mx; }
}

// ---------------------------------------------------------------------------
// One fused prep launch: cvt vf->bf16, pack stem1 W, pack six CI=32 W sets,
// and all window bounds (wmm0 nbr0, wmmD down1, wmm1 nbr1; all @128 rows).
__device__ __forceinline__ void pack_w_one(
    const float* __restrict__ W, unsigned short* __restrict__ out, int t)
{
    int lane = t & 63;
    int h = (t >> 6) & 1;
    int k = t >> 7;
    int m = lane & 15, q = lane >> 4;
    ushort8 v;
#pragma unroll
    for (int j = 0; j < 8; ++j)
        v[j] = f2bf(W[((size_t)k * 32 + q * 8 + j) * 32 + h * 16 + m]);
    *(ushort8*)(out + (size_t)t * 8) = v;
}

__global__ __launch_bounds__(256) void prep_kernel(
    const float* __restrict__ vf,
    const float* __restrict__ Ws1, const float* __restrict__ Ws2,
    const float* __restrict__ Wd,  const float* __restrict__ Wr1a,
    const float* __restrict__ Wr1b, const float* __restrict__ Wr2a,
    const float* __restrict__ Wr2b,
    const int* __restrict__ nbr0, const int* __restrict__ down1,
    const int* __restrict__ nbr1,
    unsigned short* __restrict__ xb, unsigned short* __restrict__ wp,
    int* __restrict__ wmm0, int* __restrict__ wmmD, int* __restrict__ wmm1,
    int N0, int N1)
{
    int t = blockIdx.x * 256 + threadIdx.x;
    if (t < N0) {                                   // cvt vf -> bf16
        float4 v = *(const float4*)(vf + (size_t)t * 4);
        ushortv4 r = {f2bf(v.x), f2bf(v.y), f2bf(v.z), f2bf(v.w)};
        *(ushortv4*)(xb + (size_t)t * 4) = r;
        return;
    }
    t -= N0;
    if (t < 512) {                                  // stem1 pack (taps folded into K)
        int lane = t & 63;
        int h = (t >> 6) & 1;
        int c = t >> 7;
        int m = lane & 15, q = lane >> 4;
        ushort8 v;
#pragma unroll
        for (int j = 0; j < 8; ++j) {
            int kdim = c * 32 + q * 8 + j;
            int tap = kdim >> 2, ci = kdim & 3;
            v[j] = (tap < 27) ? f2bf(Ws1[((size_t)tap * 4 + ci) * 32 + h * 16 + m]) : 0;
        }
        *(ushort8*)(wp + O_S1 + (size_t)t * 8) = v;
        return;
    }
    t -= 512;
    if (t < 27 * 128) { pack_w_one(Ws2,  wp + O_S2,  t); return; }
    t -= 27 * 128;
    if (t < 8 * 128)  { pack_w_one(Wd,   wp + O_DN,  t); return; }
    t -= 8 * 128;
    if (t < 27 * 128) { pack_w_one(Wr1a, wp + O_R1A, t); return; }
    t -= 27 * 128;
    if (t < 27 * 128) { pack_w_one(Wr1b, wp + O_R1B, t); return; }
    t -= 27 * 128;
    if (t < 27 * 128) { pack_w_one(Wr2a, wp + O_R2A, t); return; }
    t -= 27 * 128;
    if (t < 27 * 128) { pack_w_one(Wr2b, wp + O_R2B, t); return; }
    t -= 27 * 128;
    int nb0 = (N0 + 127) >> 7, nb1 = (N1 + 127) >> 7;
    if (t < nb0 * 3 * 64) { wmm_calc<3, 9>(nbr0, N0, t, wmm0); return; }
    t -= nb0 * 3 * 64;
    if (t < nb1 * 2 * 64) { wmm_calc<2, 4>(down1, N1, t, wmmD); return; }
    t -= nb1 * 2 * 64;
    if (t < nb1 * 3 * 64) { wmm_calc<3, 9>(nbr1, N1, t, wmm1); return; }
}

// ---------------------------------------------------------------------------
// Epilogue (R13-proven): scattered C-layout stores + BN partials -> LDS ->
// part[lb]. [R15: LDS-transpose + device atomics regressed -- keep this]
__device__ __forceinline__ void conv_epilogue2(
    floatx4 acc00, floatx4 acc01, floatx4 acc10, floatx4 acc11,
    unsigned short* __restrict__ y, float* __restrict__ part,
    int rowbase, int lb, int N, float* sm)
{
    const int lane = threadIdx.x & 63;
    const int m = lane & 15, q = lane >> 4;

    if (threadIdx.x < 64) sm[threadIdx.x] = 0.f;
    __syncthreads();

#pragma unroll
    for (int r = 0; r < 4; ++r) {
        int ra = rowbase + q * 4 + r;
        int rb = ra + 16;
        if (ra < N) {
            y[(size_t)ra * 32 + m]      = f2bf(acc00[r]);
            y[(size_t)ra * 32 + 16 + m] = f2bf(acc01[r]);
        }
        if (rb < N) {
            y[(size_t)rb * 32 + m]      = f2bf(acc10[r]);
            y[(size_t)rb * 32 + 16 + m] = f2bf(acc11[r]);
        }
    }

    float s0 = 0.f, q0 = 0.f, s1 = 0.f, q1 = 0.f;
#pragma unroll
    for (int r = 0; r < 4; ++r) {
        s0 += acc00[r] + acc10[r];
        q0 += acc00[r] * acc00[r] + acc10[r] * acc10[r];
        s1 += acc01[r] + acc11[r];
        q1 += acc01[r] * acc01[r] + acc11[r] * acc11[r];
    }
    s0 += __shfl_down(s0, 32); s0 += __shfl_down(s0, 16);
    q0 += __shfl_down(q0, 32); q0 += __shfl_down(q0, 16);
    s1 += __shfl_down(s1, 32); s1 += __shfl_down(s1, 16);
    q1 += __shfl_down(q1, 32); q1 += __shfl_down(q1, 16);
    if (lane < 16) {
        atomicAdd(&sm[m],      s0);
        atomicAdd(&sm[32 + m], q0);
        atomicAdd(&sm[16 + m],      s1);
        atomicAdd(&sm[48 + m], q1);
    }
    __syncthreads();
    if (threadIdx.x < 64)
        part[(size_t)lb * 64 + threadIdx.x] = sm[threadIdx.x];
}

#define MFMA_BF16 __builtin_amdgcn_mfma_f32_16x16x32_bf16

// ---------------------------------------------------------------------------
// MFMA sparse conv, round 17 = R13 structure, occupancy experiment.
//  - R16 post-mortem: dbuf pipeline cut traffic AND conflicts but dropped
//    occupancy 43->33% and lost 13us. Across R0/R13/R16 perf tracks resident
//    waves, not traffic: latency-bound. Single change here: WROWS 448->384
//    (24.6KB -> 6 blocks/CU) + launch_bounds(256,6) (VGPR cap 85; R13 used
//    48, no spill risk [R14 lesson checked]).
//  - zero-row trick [R13]: unconditional ds_read clamped to pre-zeroed row.
//  - gll 16B staging with src-side XOR chunk swizzle [R12/R13].
//  - bounds precomputed in prep [R12]; spans > 384 take global path.
template <int K>
__global__ __launch_bounds__(256, 6) void conv_mfma_kernel(
    const unsigned short* __restrict__ x,   // [Nx][32] bf16
    const int* __restrict__ nbr,            // [K][N]
    const unsigned short* __restrict__ Wp,  // packed [K][2][64][8]
    const int* __restrict__ wmmg,           // [nb][ZG][2] window bounds
    unsigned short* __restrict__ y,         // [N][32] bf16
    float* __restrict__ part, int N)
{
    constexpr int ZG  = (K == 27) ? 3 : 2;   // dz groups
    constexpr int TPG = (K == 27) ? 9 : 4;   // taps per group

    __shared__ __align__(16) unsigned short win[(WROWS + 1) * 32];
    __shared__ float sm[64];

    const int nb = (N + 127) >> 7;
    const int lb = xcd_swizzle(nb);
    const int lane = threadIdx.x & 63;
    const int wave = (int)threadIdx.x >> 6;
    const int m = lane & 15, q = lane >> 4;
    const int rb0 = lb * 128;
    const int rowbase = rb0 + wave * 32;
    const int r0 = rowbase + m;
    const int r1 = r0 + 16;
    const bool v0 = r0 < N, v1 = r1 < N;

    floatx4 c00 = {0.f, 0.f, 0.f, 0.f};
    floatx4 c01 = c00, c10 = c00, c11 = c00;

    // zero row (row index WROWS): target of all invalid/clamped A-frag reads
    if (threadIdx.x < 4) {
        short8 z = {};
        *(short8*)&win[WROWS * 32 + threadIdx.x * 8] = z;
    }

    // preload all group windows (uniform -> scalar loads, hoisted)
    int wmn[ZG], wc4[ZG];
#pragma unroll
    for (int c = 0; c < ZG; ++c) {
        int lo = wmmg[(lb * ZG + c) * 2];
        int hi = wmmg[(lb * ZG + c) * 2 + 1];
        wmn[c] = lo;
        int sp = (hi < 0) ? 0 : (hi - lo + 1);
        wc4[c] = (sp < WROWS ? sp : WROWS) * 4;
        if (hi >= 0 && hi - lo + 1 > WROWS) wc4[c] = -1;   // oversize -> global path
    }

#define IDX(k, rr, vv) ((vv) ? nbr[(size_t)(k) * N + (rr)] : -1)
// branchless LDS A-frag: clamp to zero row; swizzled chunk address
#define LG(dst, ii)                                                        \
    {                                                                      \
        unsigned rr_ = (unsigned)((ii) - wmin);                            \
        unsigned rc_ = rr_ < (unsigned)WROWS ? rr_ : (unsigned)WROWS;      \
        dst = *(const short8*)&win[rc_ * 32 + ((q ^ ((rc_ >> 1) & 3)) << 3)]; \
    }

    for (int c = 0; c < ZG; ++c) {
        const int wmin = wmn[c];
        const int sc4 = wc4[c];
        const bool use_lds = (sc4 >= 0);

        // async stage window rows -> win (swizzled global src, linear LDS dest)
        if (use_lds) {
            for (int cb = wave * 64; cb < sc4; cb += 256) {
                int cc = cb + lane;
                int rr = cc >> 2, s = cc & 3;
                int qq = s ^ ((rr >> 1) & 3);
                if (cc < sc4)
                    GLL16(x + ((size_t)(wmin + rr)) * 32 + qq * 8, win + (size_t)cb * 8);
            }
        }

        // idx loads for all TPG taps (overlap with staging DMA)
        int ia0 = (0 < TPG) ? IDX(c + ZG * 0, r0, v0) : -1;
        int ib0 = (0 < TPG) ? IDX(c + ZG * 0, r1, v1) : -1;
        int ia1 = (1 < TPG) ? IDX(c + ZG * 1, r0, v0) : -1;
        int ib1 = (1 < TPG) ? IDX(c + ZG * 1, r1, v1) : -1;
        int ia2 = (2 < TPG) ? IDX(c + ZG * 2, r0, v0) : -1;
        int ib2 = (2 < TPG) ? IDX(c + ZG * 2, r1, v1) : -1;
        int ia3 = (3 < TPG) ? IDX(c + ZG * 3, r0, v0) : -1;
        int ib3 = (3 < TPG) ? IDX(c + ZG * 3, r1, v1) : -1;
        int ia4 = (4 < TPG) ? IDX(c + ZG * 4, r0, v0) : -1;
        int ib4 = (4 < TPG) ? IDX(c + ZG * 4, r1, v1) : -1;
        int ia5 = (5 < TPG) ? IDX(c + ZG * 5, r0, v0) : -1;
        int ib5 = (5 < TPG) ? IDX(c + ZG * 5, r1, v1) : -1;
        int ia6 = (6 < TPG) ? IDX(c + ZG * 6, r0, v0) : -1;
        int ib6 = (6 < TPG) ? IDX(c + ZG * 6, r1, v1) : -1;
        int ia7 = (7 < TPG) ? IDX(c + ZG * 7, r0, v0) : -1;
        int ib7 = (7 < TPG) ? IDX(c + ZG * 7, r1, v1) : -1;
        int ia8 = (8 < TPG) ? IDX(c + ZG * 8, r0, v0) : -1;
        int ib8 = (8 < TPG) ? IDX(c + ZG * 8, r1, v1) : -1;

        __syncthreads();   // staging DMA + zero row visible to all waves

#define TAPL(J, iA, iB)                                                    \
        if (J < TPG) {                                                     \
            const short8* wk = (const short8*)(Wp + (size_t)(c + ZG * J) * 1024); \
            short8 b0 = wk[lane];                                          \
            short8 b1 = wk[64 + lane];                                     \
            short8 a0, a1;                                                 \
            LG(a0, iA); LG(a1, iB);                                        \
            c00 = MFMA_BF16(a0, b0, c00, 0, 0, 0);                         \
            c01 = MFMA_BF16(a0, b1, c01, 0, 0, 0);                         \
            c10 = MFMA_BF16(a1, b0, c10, 0, 0, 0);                         \
            c11 = MFMA_BF16(a1, b1, c11, 0, 0, 0);                         \
        }
#define TAPG(J, iA, iB)                                                    \
        if (J < TPG) {                                                     \
            const short8* wk = (const short8*)(Wp + (size_t)(c + ZG * J) * 1024); \
            short8 b0 = wk[lane];                                          \
            short8 b1 = wk[64 + lane];                                     \
            short8 a0 = gath(x, iA, q);                                    \
            short8 a1 = gath(x, iB, q);                                    \
            c00 = MFMA_BF16(a0, b0, c00, 0, 0, 0);                         \
            c01 = MFMA_BF16(a0, b1, c01, 0, 0, 0);                         \
            c10 = MFMA_BF16(a1, b0, c10, 0, 0, 0);                         \
            c11 = MFMA_BF16(a1, b1, c11, 0, 0, 0);                         \
        }
        if (use_lds) {
            TAPL(0, ia0, ib0) TAPL(1, ia1, ib1) TAPL(2, ia2, ib2)
            TAPL(3, ia3, ib3) TAPL(4, ia4, ib4) TAPL(5, ia5, ib5)
            TAPL(6, ia6, ib6) TAPL(7, ia7, ib7) TAPL(8, ia8, ib8)
        } else {
            TAPG(0, ia0, ib0) TAPG(1, ia1, ib1) TAPG(2, ia2, ib2)
            TAPG(3, ia3, ib3) TAPG(4, ia4, ib4) TAPG(5, ia5, ib5)
            TAPG(6, ia6, ib6) TAPG(7, ia7, ib7) TAPG(8, ia8, ib8)
        }
#undef TAPL
#undef TAPG

        if (c != ZG - 1) __syncthreads();   // win free for next group's stage
    }
#undef IDX
#undef LG

    conv_epilogue2(c00, c01, c10, c11, y, part, rowbase, lb, N, sm);
}

// ---------------------------------------------------------------------------
// stem1 as MFMA: CI=4, 27 taps folded into kdim = tap*4+ci, 4 chunks of K=32.
__global__ __launch_bounds__(256) void conv_stem1_mfma(
    const unsigned short* __restrict__ xb,  // [N][4] bf16
    const int* __restrict__ nbr,            // [27][N]
    const unsigned short* __restrict__ Wp,  // packed [4][2][64][8]
    unsigned short* __restrict__ y,         // [N][32] bf16
    float* __restrict__ part, int N)
{
    __shared__ float sm[64];
    const int nb = (N + 127) / 128;
    const int lb = xcd_swizzle(nb);
    const int lane = threadIdx.x & 63;
    const int wave = (int)threadIdx.x >> 6;
    const int m = lane & 15, q = lane >> 4;
    const int rowbase = lb * 128 + wave * 32;
    const int row0 = rowbase + m;
    const int row1 = rowbase + 16 + m;

    floatx4 acc00 = {0.f, 0.f, 0.f, 0.f};
    floatx4 acc01 = acc00, acc10 = acc00, acc11 = acc00;

#pragma unroll
    for (int c = 0; c < 4; ++c) {
        const int t0 = c * 8 + q * 2, t1 = t0 + 1;
        short8 a0 = {}, a1 = {};
        {
            int ia = (t0 < 27 && row0 < N) ? nbr[(size_t)t0 * N + row0] : -1;
            int ib = (t1 < 27 && row0 < N) ? nbr[(size_t)t1 * N + row0] : -1;
            ushortv4 ga = {}, gb = {};
            if (ia >= 0) ga = *(const ushortv4*)(xb + (size_t)ia * 4);
            if (ib >= 0) gb = *(const ushortv4*)(xb + (size_t)ib * 4);
            a0[0] = (short)ga[0]; a0[1] = (short)ga[1];
            a0[2] = (short)ga[2]; a0[3] = (short)ga[3];
            a0[4] = (short)gb[0]; a0[5] = (short)gb[1];
            a0[6] = (short)gb[2]; a0[7] = (short)gb[3];
        }
        {
            int ia = (t0 < 27 && row1 < N) ? nbr[(size_t)t0 * N + row1] : -1;
            int ib = (t1 < 27 && row1 < N) ? nbr[(size_t)t1 * N + row1] : -1;
            ushortv4 ga = {}, gb = {};
            if (ia >= 0) ga = *(const ushortv4*)(xb + (size_t)ia * 4);
            if (ib >= 0) gb = *(const ushortv4*)(xb + (size_t)ib * 4);
            a1[0] = (short)ga[0]; a1[1] = (short)ga[1];
            a1[2] = (short)ga[2]; a1[3] = (short)ga[3];
            a1[4] = (short)gb[0]; a1[5] = (short)gb[1];
            a1[6] = (short)gb[2]; a1[7] = (short)gb[3];
        }
        const short8* wk = (const short8*)Wp;
        short8 b0 = wk[(c * 2 + 0) * 64 + lane];
        short8 b1 = wk[(c * 2 + 1) * 64 + lane];
        acc00 = MFMA_BF16(a0, b0, acc00, 0, 0, 0);
        acc01 = MFMA_BF16(a0, b1, acc01, 0, 0, 0);
        acc10 = MFMA_BF16(a1, b0, acc10, 0, 0, 0);
        acc11 = MFMA_BF16(a1, b1, acc11, 0, 0, 0);
    }

    conv_epilogue2(acc00, acc01, acc10, acc11, y, part, rowbase, lb, N, sm);
}

// ---------------------------------------------------------------------------
// Parallel stat reduction: part[nb][64] -> atomicAdd into stats[64] (pre-zeroed).
__global__ __launch_bounds__(256) void reduce_stats_kernel(
    const float* __restrict__ part, float* __restrict__ stats, int nb)
{
    __shared__ float sm[256];
    int t = threadIdx.x;
    int c = t & 63, g = t >> 6;
    float s = 0.f;
    for (int b = blockIdx.x * 4 + g; b < nb; b += 256)
        s += part[(size_t)b * 64 + c];
    sm[t] = s;
    __syncthreads();
    if (t < 64)
        atomicAdd(&stats[t], sm[t] + sm[64 + t] + sm[128 + t] + sm[192 + t]);
}

// ---------------------------------------------------------------------------
// BN (+optional bf16 residual) + ReLU. bf16 in; bf16 or fp32 out.
template <bool OUT_F32, bool HAS_RES>
__global__ __launch_bounds__(256) void bn_relu_kernel(
    const unsigned short* __restrict__ y, const float* __restrict__ stats,
    const float* __restrict__ gamma, const float* __restrict__ beta,
    const unsigned short* __restrict__ resid, void* __restrict__ outp, int N)
{
    int t = blockIdx.x * 256 + threadIdx.x;
    if (t >= N) return;
    float inv_n = 1.0f / (float)N;
    const ushort8* yr = (const ushort8*)(y + (size_t)t * 32);

#pragma unroll
    for (int c = 0; c < 4; ++c) {
        ushort8 v = yr[c];
        ushort8 rv = {};
        if (HAS_RES) rv = ((const ushort8*)(resid + (size_t)t * 32))[c];
        float f0, f1, f2, f3, f4, f5, f6, f7;
#define BNJ(fj, j)                                                        \
        {                                                                 \
            int co = c * 8 + (j);                                         \
            float mu = stats[co] * inv_n;                                 \
            float var = stats[32 + co] * inv_n - mu * mu;                 \
            float sc = rsqrtf(var + EPS) * gamma[co];                     \
            fj = (bf2f(v[j]) - mu) * sc + beta[co];                       \
            if (HAS_RES) fj += bf2f(rv[j]);                               \
            fj = fmaxf(fj, 0.0f);                                         \
        }
        BNJ(f0, 0) BNJ(f1, 1) BNJ(f2, 2) BNJ(f3, 3)
        BNJ(f4, 4) BNJ(f5, 5) BNJ(f6, 6) BNJ(f7, 7)
#undef BNJ
        if (OUT_F32) {
            float* ob = (float*)outp + (size_t)t * 32 + c * 8;
            floatx4 u0 = {f0, f1, f2, f3}, u1 = {f4, f5, f6, f7};
            *(floatx4*)(ob) = u0;
            *(floatx4*)(ob + 4) = u1;
        } else {
            ushort8 o;
            o[0] = f2bf(f0); o[1] = f2bf(f1); o[2] = f2bf(f2); o[3] = f2bf(f3);
            o[4] = f2bf(f4); o[5] = f2bf(f5); o[6] = f2bf(f6); o[7] = f2bf(f7);
            ((ushort8*)((unsigned short*)outp + (size_t)t * 32))[c] = o;
        }
    }
}

// ---------------------------------------------------------------------------
extern "C" void kernel_launch(void* const* d_in, const int* in_sizes, int n_in,
                              void* d_out, int out_size, void* d_ws, size_t ws_size,
                              hipStream_t stream)
{
    const float* vf   = (const float*)d_in[0];
    const float* Ws1  = (const float*)d_in[1];
    const float* Ws2  = (const float*)d_in[2];
    const float* Wd   = (const float*)d_in[3];
    const float* Wr1a = (const float*)d_in[4];
    const float* Wr1b = (const float*)d_in[5];
    const float* Wr2a = (const float*)d_in[6];
    const float* Wr2b = (const float*)d_in[7];
    const float* gam  = (const float*)d_in[8];
    const float* bet  = (const float*)d_in[9];
    const int* nbr0   = (const int*)d_in[10];
    const int* down1  = (const int*)d_in[11];
    const int* nbr1   = (const int*)d_in[12];

    int N0 = in_sizes[0] / 4;
    int N1 = in_sizes[11] / 8;

    // ws layout (bf16 buffers as unsigned short)
    unsigned short* yraw = (unsigned short*)d_ws;            // N0*32
    unsigned short* actA = yraw + (size_t)N0 * 32;           // N0*32
    unsigned short* actB = actA + (size_t)N0 * 32;           // N0*32
    unsigned short* xb   = actB + (size_t)N0 * 32;           // N0*4
    unsigned short* wp   = xb + (size_t)N0 * 4;              // packed weights
    float* part  = (float*)(wp + WP_TOTAL);                  // <=3200 blocks * 64
    float* stats = part + (size_t)3200 * 64;                 // 7*64 fp32
    int nb0 = (N0 + 127) / 128;
    int nb1 = (N1 + 127) / 128;
    int* wmm0 = (int*)(stats + 7 * 64);                      // nb0*3*2 ints
    int* wmmD = wmm0 + (size_t)nb0 * 6;                      // nb1*2*2 ints
    int* wmm1 = wmmD + (size_t)nb1 * 4;                      // nb1*3*2 ints

    hipMemsetAsync(stats, 0, 7 * 64 * sizeof(float), stream);

    auto g1 = [](int n) { return dim3((unsigned)((n + 255) / 256)); };
    auto gm = [](int n) { return dim3((unsigned)((n + 127) / 128)); };   // 128 rows/block

    int prep_threads = N0 + 512 + 128 * (27 * 5 + 8) + 64 * (nb0 * 3 + nb1 * 5);
    prep_kernel<<<g1(prep_threads), 256, 0, stream>>>(
        vf, Ws1, Ws2, Wd, Wr1a, Wr1b, Wr2a, Wr2b,
        nbr0, down1, nbr1, xb, wp, wmm0, wmmD, wmm1, N0, N1);

    // stem1: xb -> yraw; act -> actA
    conv_stem1_mfma<<<gm(N0), 256, 0, stream>>>(xb, nbr0, wp + O_S1, yraw, part, N0);
    reduce_stats_kernel<<<64, 256, 0, stream>>>(part, stats + 0 * 64, nb0);
    bn_relu_kernel<false, false><<<g1(N0), 256, 0, stream>>>(yraw, stats + 0 * 64, gam + 0, bet + 0, nullptr, actA, N0);
    // stem2: actA -> yraw; act -> actB
    conv_mfma_kernel<27><<<gm(N0), 256, 0, stream>>>(actA, nbr0, wp + O_S2, wmm0, yraw, part, N0);
    reduce_stats_kernel<<<64, 256, 0, stream>>>(part, stats + 1 * 64, nb0);
    bn_relu_kernel<false, false><<<g1(N0), 256, 0, stream>>>(yraw, stats + 1 * 64, gam + 32, bet + 32, nullptr, actB, N0);
    // down: actB (N0 rows) -> yraw (N1); x1 -> actA
    conv_mfma_kernel<8><<<gm(N1), 256, 0, stream>>>(actB, down1, wp + O_DN, wmmD, yraw, part, N1);
    reduce_stats_kernel<<<64, 256, 0, stream>>>(part, stats + 2 * 64, nb1);
    bn_relu_kernel<false, false><<<g1(N1), 256, 0, stream>>>(yraw, stats + 2 * 64, gam + 64, bet + 64, nullptr, actA, N1);
    // r1a: actA -> yraw; h -> actB
    conv_mfma_kernel<27><<<gm(N1), 256, 0, stream>>>(actA, nbr1, wp + O_R1A, wmm1, yraw, part, N1);
    reduce_stats_kernel<<<64, 256, 0, stream>>>(part, stats + 3 * 64, nb1);
    bn_relu_kernel<false, false><<<g1(N1), 256, 0, stream>>>(yraw, stats + 3 * 64, gam + 96, bet + 96, nullptr, actB, N1);
    // r1b: actB -> yraw; x1' = relu(bn(yraw) + actA) -> actB
    conv_mfma_kernel<27><<<gm(N1), 256, 0, stream>>>(actB, nbr1, wp + O_R1B, wmm1, yraw, part, N1);
    reduce_stats_kernel<<<64, 256, 0, stream>>>(part, stats + 4 * 64, nb1);
    bn_relu_kernel<false, true><<<g1(N1), 256, 0, stream>>>(yraw, stats + 4 * 64, gam + 128, bet + 128, actA, actB, N1);
    // r2a: actB -> yraw; h2 -> actA
    conv_mfma_kernel<27><<<gm(N1), 256, 0, stream>>>(actB, nbr1, wp + O_R2A, wmm1, yraw, part, N1);
    reduce_stats_kernel<<<64, 256, 0, stream>>>(part, stats + 5 * 64, nb1);
    bn_relu_kernel<false, false><<<g1(N1), 256, 0, stream>>>(yraw, stats + 5 * 64, gam + 160, bet + 160, nullptr, actA, N1);
    // r2b: actA -> yraw; out = relu(bn(yraw) + actB) -> d_out (fp32)
    conv_mfma_kernel<27><<<gm(N1), 256, 0, stream>>>(actA, nbr1, wp + O_R2B, wmm1, yraw, part, N1);
    reduce_stats_kernel<<<64, 256, 0, stream>>>(part, stats + 6 * 64, nb1);
    bn_relu_kernel<true, true><<<g1(N1), 256, 0, stream>>>(yraw, stats + 6 * 64, gam + 192, bet + 192, actB, d_out, N1);
}

// Round 7
// 618.635 us; speedup vs baseline: 1.3514x; 1.3514x over previous
//
#include <hip/hip_runtime.h>

#define EPS 1e-5f
#define WROWS 384   // LDS window rows; (384+1)*64B = 24.6KB -> room for 6 blocks/CU

typedef __attribute__((ext_vector_type(8))) short short8;            // 8 bf16 MFMA frag
typedef __attribute__((ext_vector_type(4))) float floatx4;           // MFMA C/D frag
typedef __attribute__((ext_vector_type(8))) unsigned short ushort8;
typedef __attribute__((ext_vector_type(4))) unsigned short ushortv4;

// packed-weight element offsets (compile-time)
#define O_S1  0
#define O_S2  4096
#define O_DN  (O_S2 + 27648)
#define O_R1A (O_DN + 8192)
#define O_R1B (O_R1A + 27648)
#define O_R2A (O_R1B + 27648)
#define O_R2B (O_R2A + 27648)
#define WP_TOTAL (O_R2B + 27648)

// async global->LDS 16B (linear LDS dest = wave-uniform base + lane*16)
#define GLL16(g, l)                                                       \
    __builtin_amdgcn_global_load_lds(                                     \
        (const __attribute__((address_space(1))) void*)(g),               \
        (__attribute__((address_space(3))) void*)(l), 16, 0, 0)

// bf16 <-> f32 (RTNE)
__device__ __forceinline__ unsigned short f2bf(float f) {
    union { float f; unsigned u; } x; x.f = f;
    unsigned r = x.u + 0x7fffu + ((x.u >> 16) & 1u);
    return (unsigned short)(r >> 16);
}
__device__ __forceinline__ float bf2f(unsigned short b) {
    union { unsigned u; float f; } x; x.u = ((unsigned)b) << 16;
    return x.f;
}

// XCD-aware block remap [R8: halved FETCH]
__device__ __forceinline__ int xcd_swizzle(int nb) {
    int b = (int)blockIdx.x;
    int q = nb >> 3, r = nb & 7;
    int x = b & 7, i = b >> 3;
    return x * q + (x < r ? x : r) + i;
}

// guarded 16B A-fragment gather from GLOBAL (fallback path, rare)
__device__ __forceinline__ short8 gath(const unsigned short* __restrict__ x,
                                       int ii, int q) {
    short8 z = {};
    return (ii >= 0) ? *(const short8*)(x + (size_t)ii * 32 + q * 8) : z;
}

// ---------------------------------------------------------------------------
// Per-(block,group) window bounds: one wave per window, reduced via shfl.
// All convs at 128-row blocks. nbr1's result reused by 4 convs. [R12]
template <int ZG, int TPG>
__device__ __forceinline__ void wmm_calc(
    const int* __restrict__ nbr, int N, int t, int* __restrict__ out)
{
    int ln = t & 63, wv = t >> 6;
    int lb = wv / ZG, c = wv - lb * ZG;
    int base = lb * 128;
    int mn = 0x7fffffff, mx = -1;
#pragma unroll
    for (int j = 0; j < TPG; ++j) {
#pragma unroll
        for (int h = 0; h < 2; ++h) {
            int r = base + h * 64 + ln;
            if (r < N) {
                int v = nbr[(size_t)(c + ZG * j) * N + r];
                if (v >= 0) { mn = min(mn, v); mx = max(mx, v); }
            }
        }
    }
#pragma unroll
    for (int off = 32; off >= 1; off >>= 1) {
        mn = min(mn, __shfl_down(mn, off));
        mx = max(mx, __shfl_down(mx, off));
    }
    if (ln == 0) { out[wv * 2] = (mx < 0) ? 0 : mn; out[wv * 2 + 1] = mx; }
}

// ---------------------------------------------------------------------------
// One fused prep launch: cvt vf->bf16, pack stem1 W, pack six CI=32 W sets,
// and all window bounds (wmm0 nbr0, wmmD down1, wmm1 nbr1; all @128 rows).
__device__ __forceinline__ void pack_w_one(
    const float* __restrict__ W, unsigned short* __restrict__ out, int t)
{
    int lane = t & 63;
    int h = (t >> 6) & 1;
    int k = t >> 7;
    int m = lane & 15, q = lane >> 4;
    ushort8 v;
#pragma unroll
    for (int j = 0; j < 8; ++j)
        v[j] = f2bf(W[((size_t)k * 32 + q * 8 + j) * 32 + h * 16 + m]);
    *(ushort8*)(out + (size_t)t * 8) = v;
}

__global__ __launch_bounds__(256) void prep_kernel(
    const float* __restrict__ vf,
    const float* __restrict__ Ws1, const float* __restrict__ Ws2,
    const float* __restrict__ Wd,  const float* __restrict__ Wr1a,
    const float* __restrict__ Wr1b, const float* __restrict__ Wr2a,
    const float* __restrict__ Wr2b,
    const int* __restrict__ nbr0, const int* __restrict__ down1,
    const int* __restrict__ nbr1,
    unsigned short* __restrict__ xb, unsigned short* __restrict__ wp,
    int* __restrict__ wmm0, int* __restrict__ wmmD, int* __restrict__ wmm1,
    int N0, int N1)
{
    int t = blockIdx.x * 256 + threadIdx.x;
    if (t < N0) {                                   // cvt vf -> bf16
        float4 v = *(const float4*)(vf + (size_t)t * 4);
        ushortv4 r = {f2bf(v.x), f2bf(v.y), f2bf(v.z), f2bf(v.w)};
        *(ushortv4*)(xb + (size_t)t * 4) = r;
        return;
    }
    t -= N0;
    if (t < 512) {                                  // stem1 pack (taps folded into K)
        int lane = t & 63;
        int h = (t >> 6) & 1;
        int c = t >> 7;
        int m = lane & 15, q = lane >> 4;
        ushort8 v;
#pragma unroll
        for (int j = 0; j < 8; ++j) {
            int kdim = c * 32 + q * 8 + j;
            int tap = kdim >> 2, ci = kdim & 3;
            v[j] = (tap < 27) ? f2bf(Ws1[((size_t)tap * 4 + ci) * 32 + h * 16 + m]) : 0;
        }
        *(ushort8*)(wp + O_S1 + (size_t)t * 8) = v;
        return;
    }
    t -= 512;
    if (t < 27 * 128) { pack_w_one(Ws2,  wp + O_S2,  t); return; }
    t -= 27 * 128;
    if (t < 8 * 128)  { pack_w_one(Wd,   wp + O_DN,  t); return; }
    t -= 8 * 128;
    if (t < 27 * 128) { pack_w_one(Wr1a, wp + O_R1A, t); return; }
    t -= 27 * 128;
    if (t < 27 * 128) { pack_w_one(Wr1b, wp + O_R1B, t); return; }
    t -= 27 * 128;
    if (t < 27 * 128) { pack_w_one(Wr2a, wp + O_R2A, t); return; }
    t -= 27 * 128;
    if (t < 27 * 128) { pack_w_one(Wr2b, wp + O_R2B, t); return; }
    t -= 27 * 128;
    int nb0 = (N0 + 127) >> 7, nb1 = (N1 + 127) >> 7;
    if (t < nb0 * 3 * 64) { wmm_calc<3, 9>(nbr0, N0, t, wmm0); return; }
    t -= nb0 * 3 * 64;
    if (t < nb1 * 2 * 64) { wmm_calc<2, 4>(down1, N1, t, wmmD); return; }
    t -= nb1 * 2 * 64;
    if (t < nb1 * 3 * 64) { wmm_calc<3, 9>(nbr1, N1, t, wmm1); return; }
}

// ---------------------------------------------------------------------------
// Epilogue (R13-proven): scattered C-layout stores + BN partials -> LDS ->
// part[lb]. [R15: LDS-transpose + device atomics regressed -- keep this]
__device__ __forceinline__ void conv_epilogue2(
    floatx4 acc00, floatx4 acc01, floatx4 acc10, floatx4 acc11,
    unsigned short* __restrict__ y, float* __restrict__ part,
    int rowbase, int lb, int N, float* sm)
{
    const int lane = threadIdx.x & 63;
    const int m = lane & 15, q = lane >> 4;

    if (threadIdx.x < 64) sm[threadIdx.x] = 0.f;
    __syncthreads();

#pragma unroll
    for (int r = 0; r < 4; ++r) {
        int ra = rowbase + q * 4 + r;
        int rb = ra + 16;
        if (ra < N) {
            y[(size_t)ra * 32 + m]      = f2bf(acc00[r]);
            y[(size_t)ra * 32 + 16 + m] = f2bf(acc01[r]);
        }
        if (rb < N) {
            y[(size_t)rb * 32 + m]      = f2bf(acc10[r]);
            y[(size_t)rb * 32 + 16 + m] = f2bf(acc11[r]);
        }
    }

    float s0 = 0.f, q0 = 0.f, s1 = 0.f, q1 = 0.f;
#pragma unroll
    for (int r = 0; r < 4; ++r) {
        s0 += acc00[r] + acc10[r];
        q0 += acc00[r] * acc00[r] + acc10[r] * acc10[r];
        s1 += acc01[r] + acc11[r];
        q1 += acc01[r] * acc01[r] + acc11[r] * acc11[r];
    }
    s0 += __shfl_down(s0, 32); s0 += __shfl_down(s0, 16);
    q0 += __shfl_down(q0, 32); q0 += __shfl_down(q0, 16);
    s1 += __shfl_down(s1, 32); s1 += __shfl_down(s1, 16);
    q1 += __shfl_down(q1, 32); q1 += __shfl_down(q1, 16);
    if (lane < 16) {
        atomicAdd(&sm[m],      s0);
        atomicAdd(&sm[32 + m], q0);
        atomicAdd(&sm[16 + m],      s1);
        atomicAdd(&sm[48 + m], q1);
    }
    __syncthreads();
    if (threadIdx.x < 64)
        part[(size_t)lb * 64 + threadIdx.x] = sm[threadIdx.x];
}

#define MFMA_BF16 __builtin_amdgcn_mfma_f32_16x16x32_bf16

// ---------------------------------------------------------------------------
// MFMA sparse conv, round 18 = R13 structure, CLEAN occupancy experiment.
//  - R17 post-mortem: launch_bounds(...,6) forced VGPR 40 -> spills (WRITE
//    297MB, dur 127us) -- occupancy rose to 58% and it didn't matter.
//    Allocator law (3 data points): (256,5)->48 VGPR no-spill; min-waves>=6
//    ->40 VGPR spill. Inner loop needs ~48.
//  - R18 single variable vs R13: WROWS 448->384 (LDS 28.7->24.6KB). Bounds
//    stay (256,5) = proven 48-VGPR config. If HW residency reaches 6
//    blocks/CU -> win; if VGPR caps at 5 -> R13 parity, axis closed.
//  - zero-row trick [R13]; gll 16B staging + src XOR swizzle [R12/R13];
//    bounds precomputed in prep [R12]; spans > 384 take global path.
template <int K>
__global__ __launch_bounds__(256, 5) void conv_mfma_kernel(
    const unsigned short* __restrict__ x,   // [Nx][32] bf16
    const int* __restrict__ nbr,            // [K][N]
    const unsigned short* __restrict__ Wp,  // packed [K][2][64][8]
    const int* __restrict__ wmmg,           // [nb][ZG][2] window bounds
    unsigned short* __restrict__ y,         // [N][32] bf16
    float* __restrict__ part, int N)
{
    constexpr int ZG  = (K == 27) ? 3 : 2;   // dz groups
    constexpr int TPG = (K == 27) ? 9 : 4;   // taps per group

    __shared__ __align__(16) unsigned short win[(WROWS + 1) * 32];
    __shared__ float sm[64];

    const int nb = (N + 127) >> 7;
    const int lb = xcd_swizzle(nb);
    const int lane = threadIdx.x & 63;
    const int wave = (int)threadIdx.x >> 6;
    const int m = lane & 15, q = lane >> 4;
    const int rb0 = lb * 128;
    const int rowbase = rb0 + wave * 32;
    const int r0 = rowbase + m;
    const int r1 = r0 + 16;
    const bool v0 = r0 < N, v1 = r1 < N;

    floatx4 c00 = {0.f, 0.f, 0.f, 0.f};
    floatx4 c01 = c00, c10 = c00, c11 = c00;

    // zero row (row index WROWS): target of all invalid/clamped A-frag reads
    if (threadIdx.x < 4) {
        short8 z = {};
        *(short8*)&win[WROWS * 32 + threadIdx.x * 8] = z;
    }

    // preload all group windows (uniform -> scalar loads, hoisted)
    int wmn[ZG], wc4[ZG];
#pragma unroll
    for (int c = 0; c < ZG; ++c) {
        int lo = wmmg[(lb * ZG + c) * 2];
        int hi = wmmg[(lb * ZG + c) * 2 + 1];
        wmn[c] = lo;
        int sp = (hi < 0) ? 0 : (hi - lo + 1);
        wc4[c] = (sp < WROWS ? sp : WROWS) * 4;
        if (hi >= 0 && hi - lo + 1 > WROWS) wc4[c] = -1;   // oversize -> global path
    }

#define IDX(k, rr, vv) ((vv) ? nbr[(size_t)(k) * N + (rr)] : -1)
// branchless LDS A-frag: clamp to zero row; swizzled chunk address
#define LG(dst, ii)                                                        \
    {                                                                      \
        unsigned rr_ = (unsigned)((ii) - wmin);                            \
        unsigned rc_ = rr_ < (unsigned)WROWS ? rr_ : (unsigned)WROWS;      \
        dst = *(const short8*)&win[rc_ * 32 + ((q ^ ((rc_ >> 1) & 3)) << 3)]; \
    }

    for (int c = 0; c < ZG; ++c) {
        const int wmin = wmn[c];
        const int sc4 = wc4[c];
        const bool use_lds = (sc4 >= 0);

        // async stage window rows -> win (swizzled global src, linear LDS dest)
        if (use_lds) {
            for (int cb = wave * 64; cb < sc4; cb += 256) {
                int cc = cb + lane;
                int rr = cc >> 2, s = cc & 3;
                int qq = s ^ ((rr >> 1) & 3);
                if (cc < sc4)
                    GLL16(x + ((size_t)(wmin + rr)) * 32 + qq * 8, win + (size_t)cb * 8);
            }
        }

        // idx loads for all TPG taps (overlap with staging DMA)
        int ia0 = (0 < TPG) ? IDX(c + ZG * 0, r0, v0) : -1;
        int ib0 = (0 < TPG) ? IDX(c + ZG * 0, r1, v1) : -1;
        int ia1 = (1 < TPG) ? IDX(c + ZG * 1, r0, v0) : -1;
        int ib1 = (1 < TPG) ? IDX(c + ZG * 1, r1, v1) : -1;
        int ia2 = (2 < TPG) ? IDX(c + ZG * 2, r0, v0) : -1;
        int ib2 = (2 < TPG) ? IDX(c + ZG * 2, r1, v1) : -1;
        int ia3 = (3 < TPG) ? IDX(c + ZG * 3, r0, v0) : -1;
        int ib3 = (3 < TPG) ? IDX(c + ZG * 3, r1, v1) : -1;
        int ia4 = (4 < TPG) ? IDX(c + ZG * 4, r0, v0) : -1;
        int ib4 = (4 < TPG) ? IDX(c + ZG * 4, r1, v1) : -1;
        int ia5 = (5 < TPG) ? IDX(c + ZG * 5, r0, v0) : -1;
        int ib5 = (5 < TPG) ? IDX(c + ZG * 5, r1, v1) : -1;
        int ia6 = (6 < TPG) ? IDX(c + ZG * 6, r0, v0) : -1;
        int ib6 = (6 < TPG) ? IDX(c + ZG * 6, r1, v1) : -1;
        int ia7 = (7 < TPG) ? IDX(c + ZG * 7, r0, v0) : -1;
        int ib7 = (7 < TPG) ? IDX(c + ZG * 7, r1, v1) : -1;
        int ia8 = (8 < TPG) ? IDX(c + ZG * 8, r0, v0) : -1;
        int ib8 = (8 < TPG) ? IDX(c + ZG * 8, r1, v1) : -1;

        __syncthreads();   // staging DMA + zero row visible to all waves

#define TAPL(J, iA, iB)                                                    \
        if (J < TPG) {                                                     \
            const short8* wk = (const short8*)(Wp + (size_t)(c + ZG * J) * 1024); \
            short8 b0 = wk[lane];                                          \
            short8 b1 = wk[64 + lane];                                     \
            short8 a0, a1;                                                 \
            LG(a0, iA); LG(a1, iB);                                        \
            c00 = MFMA_BF16(a0, b0, c00, 0, 0, 0);                         \
            c01 = MFMA_BF16(a0, b1, c01, 0, 0, 0);                         \
            c10 = MFMA_BF16(a1, b0, c10, 0, 0, 0);                         \
            c11 = MFMA_BF16(a1, b1, c11, 0, 0, 0);                         \
        }
#define TAPG(J, iA, iB)                                                    \
        if (J < TPG) {                                                     \
            const short8* wk = (const short8*)(Wp + (size_t)(c + ZG * J) * 1024); \
            short8 b0 = wk[lane];                                          \
            short8 b1 = wk[64 + lane];                                     \
            short8 a0 = gath(x, iA, q);                                    \
            short8 a1 = gath(x, iB, q);                                    \
            c00 = MFMA_BF16(a0, b0, c00, 0, 0, 0);                         \
            c01 = MFMA_BF16(a0, b1, c01, 0, 0, 0);                         \
            c10 = MFMA_BF16(a1, b0, c10, 0, 0, 0);                         \
            c11 = MFMA_BF16(a1, b1, c11, 0, 0, 0);                         \
        }
        if (use_lds) {
            TAPL(0, ia0, ib0) TAPL(1, ia1, ib1) TAPL(2, ia2, ib2)
            TAPL(3, ia3, ib3) TAPL(4, ia4, ib4) TAPL(5, ia5, ib5)
            TAPL(6, ia6, ib6) TAPL(7, ia7, ib7) TAPL(8, ia8, ib8)
        } else {
            TAPG(0, ia0, ib0) TAPG(1, ia1, ib1) TAPG(2, ia2, ib2)
            TAPG(3, ia3, ib3) TAPG(4, ia4, ib4) TAPG(5, ia5, ib5)
            TAPG(6, ia6, ib6) TAPG(7, ia7, ib7) TAPG(8, ia8, ib8)
        }
#undef TAPL
#undef TAPG

        if (c != ZG - 1) __syncthreads();   // win free for next group's stage
    }
#undef IDX
#undef LG

    conv_epilogue2(c00, c01, c10, c11, y, part, rowbase, lb, N, sm);
}

// ---------------------------------------------------------------------------
// stem1 as MFMA: CI=4, 27 taps folded into kdim = tap*4+ci, 4 chunks of K=32.
__global__ __launch_bounds__(256) void conv_stem1_mfma(
    const unsigned short* __restrict__ xb,  // [N][4] bf16
    const int* __restrict__ nbr,            // [27][N]
    const unsigned short* __restrict__ Wp,  // packed [4][2][64][8]
    unsigned short* __restrict__ y,         // [N][32] bf16
    float* __restrict__ part, int N)
{
    __shared__ float sm[64];
    const int nb = (N + 127) / 128;
    const int lb = xcd_swizzle(nb);
    const int lane = threadIdx.x & 63;
    const int wave = (int)threadIdx.x >> 6;
    const int m = lane & 15, q = lane >> 4;
    const int rowbase = lb * 128 + wave * 32;
    const int row0 = rowbase + m;
    const int row1 = rowbase + 16 + m;

    floatx4 acc00 = {0.f, 0.f, 0.f, 0.f};
    floatx4 acc01 = acc00, acc10 = acc00, acc11 = acc00;

#pragma unroll
    for (int c = 0; c < 4; ++c) {
        const int t0 = c * 8 + q * 2, t1 = t0 + 1;
        short8 a0 = {}, a1 = {};
        {
            int ia = (t0 < 27 && row0 < N) ? nbr[(size_t)t0 * N + row0] : -1;
            int ib = (t1 < 27 && row0 < N) ? nbr[(size_t)t1 * N + row0] : -1;
            ushortv4 ga = {}, gb = {};
            if (ia >= 0) ga = *(const ushortv4*)(xb + (size_t)ia * 4);
            if (ib >= 0) gb = *(const ushortv4*)(xb + (size_t)ib * 4);
            a0[0] = (short)ga[0]; a0[1] = (short)ga[1];
            a0[2] = (short)ga[2]; a0[3] = (short)ga[3];
            a0[4] = (short)gb[0]; a0[5] = (short)gb[1];
            a0[6] = (short)gb[2]; a0[7] = (short)gb[3];
        }
        {
            int ia = (t0 < 27 && row1 < N) ? nbr[(size_t)t0 * N + row1] : -1;
            int ib = (t1 < 27 && row1 < N) ? nbr[(size_t)t1 * N + row1] : -1;
            ushortv4 ga = {}, gb = {};
            if (ia >= 0) ga = *(const ushortv4*)(xb + (size_t)ia * 4);
            if (ib >= 0) gb = *(const ushortv4*)(xb + (size_t)ib * 4);
            a1[0] = (short)ga[0]; a1[1] = (short)ga[1];
            a1[2] = (short)ga[2]; a1[3] = (short)ga[3];
            a1[4] = (short)gb[0]; a1[5] = (short)gb[1];
            a1[6] = (short)gb[2]; a1[7] = (short)gb[3];
        }
        const short8* wk = (const short8*)Wp;
        short8 b0 = wk[(c * 2 + 0) * 64 + lane];
        short8 b1 = wk[(c * 2 + 1) * 64 + lane];
        acc00 = MFMA_BF16(a0, b0, acc00, 0, 0, 0);
        acc01 = MFMA_BF16(a0, b1, acc01, 0, 0, 0);
        acc10 = MFMA_BF16(a1, b0, acc10, 0, 0, 0);
        acc11 = MFMA_BF16(a1, b1, acc11, 0, 0, 0);
    }

    conv_epilogue2(acc00, acc01, acc10, acc11, y, part, rowbase, lb, N, sm);
}

// ---------------------------------------------------------------------------
// Parallel stat reduction: part[nb][64] -> atomicAdd into stats[64] (pre-zeroed).
__global__ __launch_bounds__(256) void reduce_stats_kernel(
    const float* __restrict__ part, float* __restrict__ stats, int nb)
{
    __shared__ float sm[256];
    int t = threadIdx.x;
    int c = t & 63, g = t >> 6;
    float s = 0.f;
    for (int b = blockIdx.x * 4 + g; b < nb; b += 256)
        s += part[(size_t)b * 64 + c];
    sm[t] = s;
    __syncthreads();
    if (t < 64)
        atomicAdd(&stats[t], sm[t] + sm[64 + t] + sm[128 + t] + sm[192 + t]);
}

// ---------------------------------------------------------------------------
// BN (+optional bf16 residual) + ReLU. bf16 in; bf16 or fp32 out.
template <bool OUT_F32, bool HAS_RES>
__global__ __launch_bounds__(256) void bn_relu_kernel(
    const unsigned short* __restrict__ y, const float* __restrict__ stats,
    const float* __restrict__ gamma, const float* __restrict__ beta,
    const unsigned short* __restrict__ resid, void* __restrict__ outp, int N)
{
    int t = blockIdx.x * 256 + threadIdx.x;
    if (t >= N) return;
    float inv_n = 1.0f / (float)N;
    const ushort8* yr = (const ushort8*)(y + (size_t)t * 32);

#pragma unroll
    for (int c = 0; c < 4; ++c) {
        ushort8 v = yr[c];
        ushort8 rv = {};
        if (HAS_RES) rv = ((const ushort8*)(resid + (size_t)t * 32))[c];
        float f0, f1, f2, f3, f4, f5, f6, f7;
#define BNJ(fj, j)                                                        \
        {                                                                 \
            int co = c * 8 + (j);                                         \
            float mu = stats[co] * inv_n;                                 \
            float var = stats[32 + co] * inv_n - mu * mu;                 \
            float sc = rsqrtf(var + EPS) * gamma[co];                     \
            fj = (bf2f(v[j]) - mu) * sc + beta[co];                       \
            if (HAS_RES) fj += bf2f(rv[j]);                               \
            fj = fmaxf(fj, 0.0f);                                         \
        }
        BNJ(f0, 0) BNJ(f1, 1) BNJ(f2, 2) BNJ(f3, 3)
        BNJ(f4, 4) BNJ(f5, 5) BNJ(f6, 6) BNJ(f7, 7)
#undef BNJ
        if (OUT_F32) {
            float* ob = (float*)outp + (size_t)t * 32 + c * 8;
            floatx4 u0 = {f0, f1, f2, f3}, u1 = {f4, f5, f6, f7};
            *(floatx4*)(ob) = u0;
            *(floatx4*)(ob + 4) = u1;
        } else {
            ushort8 o;
            o[0] = f2bf(f0); o[1] = f2bf(f1); o[2] = f2bf(f2); o[3] = f2bf(f3);
            o[4] = f2bf(f4); o[5] = f2bf(f5); o[6] = f2bf(f6); o[7] = f2bf(f7);
            ((ushort8*)((unsigned short*)outp + (size_t)t * 32))[c] = o;
        }
    }
}

// ---------------------------------------------------------------------------
extern "C" void kernel_launch(void* const* d_in, const int* in_sizes, int n_in,
                              void* d_out, int out_size, void* d_ws, size_t ws_size,
                              hipStream_t stream)
{
    const float* vf   = (const float*)d_in[0];
    const float* Ws1  = (const float*)d_in[1];
    const float* Ws2  = (const float*)d_in[2];
    const float* Wd   = (const float*)d_in[3];
    const float* Wr1a = (const float*)d_in[4];
    const float* Wr1b = (const float*)d_in[5];
    const float* Wr2a = (const float*)d_in[6];
    const float* Wr2b = (const float*)d_in[7];
    const float* gam  = (const float*)d_in[8];
    const float* bet  = (const float*)d_in[9];
    const int* nbr0   = (const int*)d_in[10];
    const int* down1  = (const int*)d_in[11];
    const int* nbr1   = (const int*)d_in[12];

    int N0 = in_sizes[0] / 4;
    int N1 = in_sizes[11] / 8;

    // ws layout (bf16 buffers as unsigned short)
    unsigned short* yraw = (unsigned short*)d_ws;            // N0*32
    unsigned short* actA = yraw + (size_t)N0 * 32;           // N0*32
    unsigned short* actB = actA + (size_t)N0 * 32;           // N0*32
    unsigned short* xb   = actB + (size_t)N0 * 32;           // N0*4
    unsigned short* wp   = xb + (size_t)N0 * 4;              // packed weights
    float* part  = (float*)(wp + WP_TOTAL);                  // <=3200 blocks * 64
    float* stats = part + (size_t)3200 * 64;                 // 7*64 fp32
    int nb0 = (N0 + 127) / 128;
    int nb1 = (N1 + 127) / 128;
    int* wmm0 = (int*)(stats + 7 * 64);                      // nb0*3*2 ints
    int* wmmD = wmm0 + (size_t)nb0 * 6;                      // nb1*2*2 ints
    int* wmm1 = wmmD + (size_t)nb1 * 4;                      // nb1*3*2 ints

    hipMemsetAsync(stats, 0, 7 * 64 * sizeof(float), stream);

    auto g1 = [](int n) { return dim3((unsigned)((n + 255) / 256)); };
    auto gm = [](int n) { return dim3((unsigned)((n + 127) / 128)); };   // 128 rows/block

    int prep_threads = N0 + 512 + 128 * (27 * 5 + 8) + 64 * (nb0 * 3 + nb1 * 5);
    prep_kernel<<<g1(prep_threads), 256, 0, stream>>>(
        vf, Ws1, Ws2, Wd, Wr1a, Wr1b, Wr2a, Wr2b,
        nbr0, down1, nbr1, xb, wp, wmm0, wmmD, wmm1, N0, N1);

    // stem1: xb -> yraw; act -> actA
    conv_stem1_mfma<<<gm(N0), 256, 0, stream>>>(xb, nbr0, wp + O_S1, yraw, part, N0);
    reduce_stats_kernel<<<64, 256, 0, stream>>>(part, stats + 0 * 64, nb0);
    bn_relu_kernel<false, false><<<g1(N0), 256, 0, stream>>>(yraw, stats + 0 * 64, gam + 0, bet + 0, nullptr, actA, N0);
    // stem2: actA -> yraw; act -> actB
    conv_mfma_kernel<27><<<gm(N0), 256, 0, stream>>>(actA, nbr0, wp + O_S2, wmm0, yraw, part, N0);
    reduce_stats_kernel<<<64, 256, 0, stream>>>(part, stats + 1 * 64, nb0);
    bn_relu_kernel<false, false><<<g1(N0), 256, 0, stream>>>(yraw, stats + 1 * 64, gam + 32, bet + 32, nullptr, actB, N0);
    // down: actB (N0 rows) -> yraw (N1); x1 -> actA
    conv_mfma_kernel<8><<<gm(N1), 256, 0, stream>>>(actB, down1, wp + O_DN, wmmD, yraw, part, N1);
    reduce_stats_kernel<<<64, 256, 0, stream>>>(part, stats + 2 * 64, nb1);
    bn_relu_kernel<false, false><<<g1(N1), 256, 0, stream>>>(yraw, stats + 2 * 64, gam + 64, bet + 64, nullptr, actA, N1);
    // r1a: actA -> yraw; h -> actB
    conv_mfma_kernel<27><<<gm(N1), 256, 0, stream>>>(actA, nbr1, wp + O_R1A, wmm1, yraw, part, N1);
    reduce_stats_kernel<<<64, 256, 0, stream>>>(part, stats + 3 * 64, nb1);
    bn_relu_kernel<false, false><<<g1(N1), 256, 0, stream>>>(yraw, stats + 3 * 64, gam + 96, bet + 96, nullptr, actB, N1);
    // r1b: actB -> yraw; x1' = relu(bn(yraw) + actA) -> actB
    conv_mfma_kernel<27><<<gm(N1), 256, 0, stream>>>(actB, nbr1, wp + O_R1B, wmm1, yraw, part, N1);
    reduce_stats_kernel<<<64, 256, 0, stream>>>(part, stats + 4 * 64, nb1);
    bn_relu_kernel<false, true><<<g1(N1), 256, 0, stream>>>(yraw, stats + 4 * 64, gam + 128, bet + 128, actA, actB, N1);
    // r2a: actB -> yraw; h2 -> actA
    conv_mfma_kernel<27><<<gm(N1), 256, 0, stream>>>(actB, nbr1, wp + O_R2A, wmm1, yraw, part, N1);
    reduce_stats_kernel<<<64, 256, 0, stream>>>(part, stats + 5 * 64, nb1);
    bn_relu_kernel<false, false><<<g1(N1), 256, 0, stream>>>(yraw, stats + 5 * 64, gam + 160, bet + 160, nullptr, actA, N1);
    // r2b: actA -> yraw; out = relu(bn(yraw) + actB) -> d_out (fp32)
    conv_mfma_kernel<27><<<gm(N1), 256, 0, stream>>>(actA, nbr1, wp + O_R2B, wmm1, yraw, part, N1);
    reduce_stats_kernel<<<64, 256, 0, stream>>>(part, stats + 6 * 64, nb1);
    bn_relu_kernel<true, true><<<g1(N1), 256, 0, stream>>>(yraw, stats + 6 * 64, gam + 192, bet + 192, actB, d_out, N1);
}